// Round 1
// baseline (549.213 us; speedup 1.0000x reference)
//
#include <hip/hip_runtime.h>

#define KK 5
#define NB 4
#define NC 64
#define NH 128
#define NW 128
#define W4 (NW / 4)          // 32 float4-groups per row
#define HW (NH * NW)         // 16384
#define CHW (NC * HW)        // 1,048,576 elements (4 MB) — stride between K^2 slices

// One thread computes 4 consecutive output pixels along w.
// out[b,c,h,w] = sum_{i,j} core[b, i*5+j, c, h, w] * data_padded[b, c, h+i-2, w+j-2]
__global__ __launch_bounds__(256) void kconv_kernel(const float* __restrict__ data,
                                                    const float* __restrict__ core,
                                                    float* __restrict__ out) {
    int tid = blockIdx.x * blockDim.x + threadIdx.x;   // 0 .. 1,048,575
    int w4 = tid & (W4 - 1);
    int h  = (tid >> 5) & (NH - 1);
    int c  = (tid >> 12) & (NC - 1);
    int b  = tid >> 18;

    int wbase = w4 << 2;

    const float* dbase = data + (size_t)(b * NC + c) * HW;
    // core layout: [B, 25, C, H, W] -> offset = ((b*25 + k)*C + c)*HW + h*W + w
    const float* cbase = core + (size_t)(b * KK * KK + 0) * (size_t)CHW
                              + (size_t)c * HW + h * NW + wbase;

    float4 acc = make_float4(0.f, 0.f, 0.f, 0.f);

    #pragma unroll
    for (int i = 0; i < KK; ++i) {
        int hh = h + i - 2;
        float d[8];
        bool row_ok = (hh >= 0) && (hh < NH);
        const float* row = dbase + hh * NW + (wbase - 2);
        #pragma unroll
        for (int t = 0; t < 8; ++t) {
            int col = wbase - 2 + t;
            bool ok = row_ok && (col >= 0) && (col < NW);
            d[t] = ok ? row[t] : 0.f;
        }
        #pragma unroll
        for (int j = 0; j < KK; ++j) {
            int k = i * KK + j;
            const float4 ck = *reinterpret_cast<const float4*>(cbase + (size_t)k * CHW);
            acc.x = fmaf(ck.x, d[j + 0], acc.x);
            acc.y = fmaf(ck.y, d[j + 1], acc.y);
            acc.z = fmaf(ck.z, d[j + 2], acc.z);
            acc.w = fmaf(ck.w, d[j + 3], acc.w);
        }
    }

    float4* op = reinterpret_cast<float4*>(out + (size_t)(b * NC + c) * HW + h * NW + wbase);
    *op = acc;
}

extern "C" void kernel_launch(void* const* d_in, const int* in_sizes, int n_in,
                              void* d_out, int out_size, void* d_ws, size_t ws_size,
                              hipStream_t stream) {
    const float* data = (const float*)d_in[0];   // [4, 64, 128, 128]
    const float* core = (const float*)d_in[1];   // [4, 25*64, 128, 128]
    float* out = (float*)d_out;                  // [4, 64, 128, 128]

    int total_threads = NB * NC * NH * W4;       // 1,048,576
    dim3 block(256);
    dim3 grid(total_threads / 256);              // 4096 blocks
    kconv_kernel<<<grid, block, 0, stream>>>(data, core, out);
}

// Round 2
// 546.069 us; speedup vs baseline: 1.0058x; 1.0058x over previous
//
#include <hip/hip_runtime.h>

#define KK 5
#define NB 4
#define NC 64
#define NH 128
#define NW 128
#define HW (NH * NW)         // 16384
#define CHW (NC * HW)        // 1,048,576 elements (4 MB) — stride between K^2 slices
#define RPB 8                // output rows per block
#define LROWS (RPB + 4)      // 12 = 8 rows + 2 halo top + 2 halo bottom
#define LW 132               // 128 + 2 halo each side

typedef float vfloat4 __attribute__((ext_vector_type(4)));

// Block: 256 threads = 32 w-groups (x4 pixels) × 8 rows; covers one (b,c) strip of 8 rows.
// Grid: B*C*(H/8) = 4*64*16 = 4096 blocks.
// out[b,c,h,w] = sum_{i,j} core[b, i*5+j, c, h, w] * data_pad[b, c, h+i-2, w+j-2]
__global__ __launch_bounds__(256, 4) void kconv_kernel(const float* __restrict__ data,
                                                       const float* __restrict__ core,
                                                       float* __restrict__ out) {
    __shared__ float sdata[LROWS][LW];   // 12*132*4 = 6336 B

    const int tid = threadIdx.x;
    const int blk = blockIdx.x;
    const int hblk = blk & (NH / RPB - 1);       // 0..15
    const int c    = (blk >> 4) & (NC - 1);      // 0..63
    const int b    = blk >> 10;                  // 0..3
    const int h0   = hblk * RPB;

    const float* dbase = data + (size_t)(b * NC + c) * HW;

    // Cooperative stage of the 12x132 data window (global rows h0-2..h0+9, cols -2..129).
    #pragma unroll
    for (int idx = tid; idx < LROWS * LW; idx += 256) {
        int r   = idx / LW;
        int col = idx - r * LW;
        int gh  = h0 + r - 2;
        int gw  = col - 2;
        float v = 0.f;
        if (gh >= 0 && gh < NH && gw >= 0 && gw < NW)
            v = dbase[gh * NW + gw];
        sdata[r][col] = v;
    }
    __syncthreads();

    const int w4    = tid & 31;          // 0..31
    const int hr    = tid >> 5;          // 0..7
    const int h     = h0 + hr;
    const int wbase = w4 << 2;

    // core layout: [B, 25, C, H, W] -> ((b*25 + k)*C + c)*HW + h*W + w
    const float* cbase = core + (size_t)b * (KK * KK) * (size_t)CHW
                              + (size_t)c * HW + (size_t)(h * NW + wbase);

    vfloat4 acc = {0.f, 0.f, 0.f, 0.f};

    #pragma unroll
    for (int i = 0; i < KK; ++i) {
        // global row h+i-2 = h0 + (hr+i) - 2  ->  LDS row (hr+i); padded col: global (wbase-2) -> LDS wbase
        const float* lrow = &sdata[hr + i][wbase];
        vfloat4 d0 = *reinterpret_cast<const vfloat4*>(lrow);       // cols wbase-2 .. wbase+1
        vfloat4 d1 = *reinterpret_cast<const vfloat4*>(lrow + 4);   // cols wbase+2 .. wbase+5
        float d[8] = {d0.x, d0.y, d0.z, d0.w, d1.x, d1.y, d1.z, d1.w};
        #pragma unroll
        for (int j = 0; j < KK; ++j) {
            const int k = i * KK + j;
            vfloat4 ck = __builtin_nontemporal_load(
                reinterpret_cast<const vfloat4*>(cbase + (size_t)k * CHW));
            acc.x = fmaf(ck.x, d[j + 0], acc.x);
            acc.y = fmaf(ck.y, d[j + 1], acc.y);
            acc.z = fmaf(ck.z, d[j + 2], acc.z);
            acc.w = fmaf(ck.w, d[j + 3], acc.w);
        }
    }

    vfloat4* op = reinterpret_cast<vfloat4*>(out + (size_t)(b * NC + c) * HW
                                                 + (size_t)(h * NW + wbase));
    __builtin_nontemporal_store(acc, op);
}

extern "C" void kernel_launch(void* const* d_in, const int* in_sizes, int n_in,
                              void* d_out, int out_size, void* d_ws, size_t ws_size,
                              hipStream_t stream) {
    const float* data = (const float*)d_in[0];   // [4, 64, 128, 128]
    const float* core = (const float*)d_in[1];   // [4, 25*64, 128, 128]
    float* out = (float*)d_out;                  // [4, 64, 128, 128]

    dim3 block(256);
    dim3 grid(NB * NC * (NH / RPB));             // 4096 blocks
    kconv_kernel<<<grid, block, 0, stream>>>(data, core, out);
}